// Round 9
// baseline (165.965 us; speedup 1.0000x reference)
//
#include <hip/hip_runtime.h>
#include <stdint.h>

// ---------------------------------------------------------------------------
// AttentionHead: out = softmax_causal((Xq WQ)(Xk WK)^T / sqrt(D)) (Xv WV)
// B=4, S=2048, D=1024.  bf16 MFMA 16x16x32 (r5 body, 0-conflict), f32 accum.
// Round 9: cvt3 deleted — f32->bf16 conversion fused into qkvt staging.
//   f32 operand reg-staged (global->reg, cvt, swizzled ds_write);
//   bf16 weight operand stays on global_load_lds.  New counted-vmcnt ledger:
//   top: REG(u+1)=R outstanding; +DMA(u+1)=D; vmcnt(D) -> cvt+write; +REG(u+2);
//   compute; vmcnt(R) retires DMA; lgkm0; barrier.  One barrier per K-tile.
// ---------------------------------------------------------------------------

typedef __attribute__((ext_vector_type(8))) short short8;
typedef __attribute__((ext_vector_type(8))) unsigned short ushort8;
typedef __attribute__((ext_vector_type(4))) float f32x4;
typedef __attribute__((ext_vector_type(4))) unsigned int uint4v;

__device__ __forceinline__ unsigned short f2bf(float f) {
  union { float f; unsigned u; } v; v.f = f;
  unsigned u = v.u + 0x7FFFu + ((v.u >> 16) & 1u);   // RNE
  return (unsigned short)(u >> 16);
}
__device__ __forceinline__ float bf2f(unsigned short h) {
  union { unsigned u; float f; } v; v.u = ((unsigned)h) << 16;
  return v.f;
}
__device__ __forceinline__ unsigned pk2(float lo, float hi) {
  return (unsigned)f2bf(lo) | ((unsigned)f2bf(hi) << 16);
}

__device__ __forceinline__ void gload16(const void* g, void* l) {
  __builtin_amdgcn_global_load_lds(
      (const __attribute__((address_space(1))) unsigned int*)g,
      (__attribute__((address_space(3))) unsigned int*)l, 16, 0, 0);
}

template<int N> __device__ __forceinline__ void vmwait() {
  static_assert(N >= 0 && N <= 8, "vmcnt range");
  if constexpr (N == 0) asm volatile("s_waitcnt vmcnt(0)" ::: "memory");
  else if constexpr (N == 1) asm volatile("s_waitcnt vmcnt(1)" ::: "memory");
  else if constexpr (N == 2) asm volatile("s_waitcnt vmcnt(2)" ::: "memory");
  else if constexpr (N == 3) asm volatile("s_waitcnt vmcnt(3)" ::: "memory");
  else if constexpr (N == 4) asm volatile("s_waitcnt vmcnt(4)" ::: "memory");
  else if constexpr (N == 5) asm volatile("s_waitcnt vmcnt(5)" ::: "memory");
  else if constexpr (N == 6) asm volatile("s_waitcnt vmcnt(6)" ::: "memory");
  else if constexpr (N == 7) asm volatile("s_waitcnt vmcnt(7)" ::: "memory");
  else asm volatile("s_waitcnt vmcnt(8)" ::: "memory");
}
__device__ __forceinline__ void barrier_() { asm volatile("s_barrier" ::: "memory"); }
__device__ __forceinline__ void lgkm0() { asm volatile("s_waitcnt lgkmcnt(0)" ::: "memory"); }

// ---------------- weight transpose x3: WT[e][k] = W[k][e]*scale -------------
__global__ __launch_bounds__(256)
void wtrans3(const float* __restrict__ WQ, const float* __restrict__ WK,
             const float* __restrict__ WV,
             unsigned short* __restrict__ WQT, unsigned short* __restrict__ WKT,
             unsigned short* __restrict__ WVT) {
  const int z = blockIdx.z;
  const float* W = z == 0 ? WQ : z == 1 ? WK : WV;
  unsigned short* WT = z == 0 ? WQT : z == 1 ? WKT : WVT;
  const float scale = z == 0 ? 0.03125f : 1.0f;    // 1/sqrt(1024) into WQT
  __shared__ float t[32][33];
  const int bk = blockIdx.x * 32, be = blockIdx.y * 32;
  const int tx = threadIdx.x, ty = threadIdx.y;    // (32,8)
#pragma unroll
  for (int j = 0; j < 32; j += 8)
    t[ty + j][tx] = W[(long)(bk + ty + j) * 1024 + (be + tx)];
  __syncthreads();
#pragma unroll
  for (int j = 0; j < 32; j += 8)
    WT[(long)(be + ty + j) * 1024 + (bk + tx)] = f2bf(t[tx][ty + j] * scale);
}

// ---------------- mode0: B^T-layout bf16 GEMM (r5 body, proven 0-conflict) --
// C[m][n] = sum_k A[m][k]*B[n][k].  BM=MF*32, BN=NF*64.  8 waves (2Mx4N).
// LDS [buf][khalf][row][32]; 16B-slot swizzle ^((row>>1)&3).
template<typename CT, int MF, int NF>
__device__ __forceinline__ void gemm_body(const unsigned short* __restrict__ A,
                                          const unsigned short* __restrict__ B,
                                          CT* __restrict__ C,
                                          int bm, int bn, int kmax,
                                          int lda, int ldb, int ldc,
                                          char* AL, char* BL) {
  constexpr int BM = MF * 32, BN = NF * 64;
  constexpr int LA = BM / 128, LB = BN / 128;      // gloads per k-half
  constexpr int V = 2 * LA + LB;                   // steady-state vmcnt

  const int tid = threadIdx.x;                     // 0..511
  const int lane = tid & 63, wid = tid >> 6;
  const int wr = wid >> 2, wc = wid & 3;           // 2x4 wave grid
  const int fr = lane & 15, fq = lane >> 4;
  const int srow = tid >> 2;                       // staging row 0..127
  const int scol = (((tid & 3) ^ ((tid >> 3) & 3)) << 3);  // pre-swz src col
  const int m0 = bm * BM, n0 = bn * BN;
  const int nt = kmax >> 6;

  f32x4 acc[MF][NF] = {};

  const unsigned short* As = A + (long)(m0 + srow) * lda + scol;
  const unsigned short* Bs = B + (long)(n0 + srow) * ldb + scol;

  auto stageA = [&](int b, int h, int kt) {        // A k-half h of tile kt
#pragma unroll
    for (int l = 0; l < LA; ++l)
      gload16(As + (long)l * 128 * lda + kt * 64 + h * 32,
              AL + b * (BM * 128) + h * (BM * 64) + l * 8192 + tid * 16);
  };
  auto stageB = [&](int b, int h, int kt) {
#pragma unroll
    for (int l = 0; l < LB; ++l)
      gload16(Bs + (long)l * 128 * ldb + kt * 64 + h * 32,
              BL + b * (BN * 128) + h * (BN * 64) + l * 8192 + tid * 16);
  };

  const int aoff = (wr * (BM / 2) + fr) * 64 + ((fq ^ ((fr >> 1) & 3)) << 4);
  const int boff = (wc * (BN / 4) + fr) * 64 + ((fq ^ ((fr >> 1) & 3)) << 4);
  auto ardf = [&](int b, int kk, int m) -> short8 {
    return *(const short8*)(AL + b * (BM * 128) + kk * (BM * 64) + aoff + m * 1024);
  };
  auto brdf = [&](int b, int kk, int n) -> short8 {
    return *(const short8*)(BL + b * (BN * 128) + kk * (BN * 64) + boff + n * 1024);
  };

  // prologue: tile 0 -> buf 0   (order: A-k0, B-k0, A-k1, B-k1)
  stageA(0, 0, 0); stageB(0, 0, 0); stageA(0, 1, 0); stageB(0, 1, 0);

  for (int u = 0; u < nt; ++u) {
    const int cb = u & 1, nb = cb ^ 1;
    const bool pf = (u + 1 < nt);
    lgkm0();                                   // my ds_reads of buf nb serviced
    barrier_();                                // all waves done reading buf nb
    if (pf) { stageA(nb, 0, u + 1); vmwait<V>(); }   // retire tile-u k0 halves
    else    { vmwait<LA + LB>(); }
    barrier_();                                // k-half 0 resident for all
    short8 bfr[NF], af[MF / 2];
#pragma unroll
    for (int n = 0; n < NF; ++n) bfr[n] = brdf(cb, 0, n);
#pragma unroll
    for (int m = 0; m < MF / 2; ++m) af[m] = ardf(cb, 0, m);
    if (pf) stageB(nb, 0, u + 1);
    __builtin_amdgcn_s_setprio(1);
#pragma unroll
    for (int m = 0; m < MF / 2; ++m)
#pragma unroll
      for (int n = 0; n < NF; ++n)
        acc[m][n] = __builtin_amdgcn_mfma_f32_16x16x32_bf16(af[m], bfr[n], acc[m][n], 0, 0, 0);
    __builtin_amdgcn_s_setprio(0);
#pragma unroll
    for (int m = 0; m < MF / 2; ++m) af[m] = ardf(cb, 0, MF / 2 + m);
    if (pf) stageA(nb, 1, u + 1);
    __builtin_amdgcn_s_setprio(1);
#pragma unroll
    for (int m = 0; m < MF / 2; ++m)
#pragma unroll
      for (int n = 0; n < NF; ++n)
        acc[MF / 2 + m][n] =
            __builtin_amdgcn_mfma_f32_16x16x32_bf16(af[m], bfr[n], acc[MF / 2 + m][n], 0, 0, 0);
    __builtin_amdgcn_s_setprio(0);
    if (pf) vmwait<V>(); else vmwait<0>();     // retire tile-u k1 halves
    barrier_();                                // k-half 1 resident for all
#pragma unroll
    for (int n = 0; n < NF; ++n) bfr[n] = brdf(cb, 1, n);
#pragma unroll
    for (int m = 0; m < MF / 2; ++m) af[m] = ardf(cb, 1, m);
    if (pf) stageB(nb, 1, u + 1);
    __builtin_amdgcn_s_setprio(1);
#pragma unroll
    for (int m = 0; m < MF / 2; ++m)
#pragma unroll
      for (int n = 0; n < NF; ++n)
        acc[m][n] = __builtin_amdgcn_mfma_f32_16x16x32_bf16(af[m], bfr[n], acc[m][n], 0, 0, 0);
    __builtin_amdgcn_s_setprio(0);
#pragma unroll
    for (int m = 0; m < MF / 2; ++m) af[m] = ardf(cb, 1, MF / 2 + m);
    __builtin_amdgcn_s_setprio(1);
#pragma unroll
    for (int m = 0; m < MF / 2; ++m)
#pragma unroll
      for (int n = 0; n < NF; ++n)
        acc[MF / 2 + m][n] =
            __builtin_amdgcn_mfma_f32_16x16x32_bf16(af[m], bfr[n], acc[MF / 2 + m][n], 0, 0, 0);
    __builtin_amdgcn_s_setprio(0);
  }

  // C/D layout: col = lane&15, row = (lane>>4)*4 + reg
#pragma unroll
  for (int m = 0; m < MF; ++m) {
    const int row = m0 + wr * (BM / 2) + m * 16 + fq * 4;
#pragma unroll
    for (int n = 0; n < NF; ++n) {
      const int col = n0 + wc * (BN / 4) + n * 16 + fr;
#pragma unroll
      for (int r = 0; r < 4; ++r) {
        float v = acc[m][n][r];
        if constexpr (sizeof(CT) == 2)
          C[(long)(row + r) * ldc + col] = (CT)f2bf(v);
        else
          C[(long)(row + r) * ldc + col] = (CT)v;
      }
    }
  }
}

// ---------------- fused-cvt GEMM: one operand is f32, reg-staged ------------
// BREG=false: A = X (f32, reg-staged), B = W (bf16, DMA).
// BREG=true:  A = W (bf16, DMA),       B = X (f32, reg-staged).
// Both reg-staged operands here have 256 rows (W=2).  Ledger per iter:
//   top: REG(u+1)[R] outstanding; +DMA(u+1)[D]; vmcnt(D); cvt+ds_write;
//   +REG(u+2)[R]; compute(cb); vmcnt(R) retires DMA; lgkm0; barrier.
template<int MF, int NF, bool BREG>
__device__ __forceinline__ void gemm_fused(const float* __restrict__ X,
                                           const unsigned short* __restrict__ Wt,
                                           unsigned short* __restrict__ C,
                                           int bm, int bn, int kmax,
                                           int ldx, int ldw, int ldc,
                                           char* AL, char* BL) {
  constexpr int BM = MF * 32, BN = NF * 64;
  constexpr int DROWS = BREG ? BM : BN;            // DMA-side rows
  constexpr int RROWS = BREG ? BN : BM;            // reg-side rows (=256 here)
  constexpr int DR = DROWS / 128;                  // DMA loads per k-half
  constexpr int D = 2 * DR;                        // DMA loads per K-tile
  constexpr int WW = RROWS / 128;                  // reg writes per k-half
  constexpr int R = 4 * WW;                        // reg loads per K-tile
  static_assert(WW == 2, "reg operand must be 256 rows");

  const int tid = threadIdx.x;
  const int lane = tid & 63, wid = tid >> 6;
  const int wr = wid >> 2, wc = wid & 3;
  const int fr = lane & 15, fq = lane >> 4;
  const int srow = tid >> 2;
  const int key = (tid >> 3) & 3;                  // = ((srow)>>1)&3
  const int scol = ((tid & 3) ^ key) << 3;         // pre-swz col (bf16 elems / f32 elems)
  const int m0 = bm * BM, n0 = bn * BN;
  const int nt = kmax >> 6;

  f32x4 acc[MF][NF] = {};

  char* DL = BREG ? AL : BL;                       // DMA dest
  char* RL = BREG ? BL : AL;                       // reg-staged dest
  const int d0 = BREG ? m0 : n0;
  const int r0 = BREG ? n0 : m0;
  const unsigned short* Ws = Wt + (long)(d0 + srow) * ldw + scol;
  const float* Xs = X + (long)(r0 + srow) * ldx + scol;   // scol in f32 elems

  auto stageDMA = [&](int b, int kt) {
#pragma unroll
    for (int h = 0; h < 2; ++h)
#pragma unroll
      for (int l = 0; l < DR; ++l)
        gload16(Ws + (long)l * 128 * ldw + kt * 64 + h * 32,
                DL + b * (DROWS * 128) + h * (DROWS * 64) + l * 8192 + tid * 16);
  };

  float4 rv[2][2][2];                              // [half][w][part]
  auto issueREG = [&](int kt) {
#pragma unroll
    for (int h = 0; h < 2; ++h)
#pragma unroll
      for (int w = 0; w < 2; ++w) {
        const float* p = Xs + (long)w * 128 * ldx + kt * 64 + h * 32;
        rv[h][w][0] = *(const float4*)p;
        rv[h][w][1] = *(const float4*)(p + 4);
      }
  };
  auto writeREG = [&](int b) {
#pragma unroll
    for (int h = 0; h < 2; ++h)
#pragma unroll
      for (int w = 0; w < 2; ++w) {
        uint4v q;
        q[0] = pk2(rv[h][w][0].x, rv[h][w][0].y);
        q[1] = pk2(rv[h][w][0].z, rv[h][w][0].w);
        q[2] = pk2(rv[h][w][1].x, rv[h][w][1].y);
        q[3] = pk2(rv[h][w][1].z, rv[h][w][1].w);
        *(uint4v*)(RL + b * (RROWS * 128) + h * (RROWS * 64) + w * 8192 + tid * 16) = q;
      }
  };

  const int aoff = (wr * (BM / 2) + fr) * 64 + ((fq ^ ((fr >> 1) & 3)) << 4);
  const int boff = (wc * (BN / 4) + fr) * 64 + ((fq ^ ((fr >> 1) & 3)) << 4);
  auto ardf = [&](int b, int kk, int m) -> short8 {
    return *(const short8*)(AL + b * (BM * 128) + kk * (BM * 64) + aoff + m * 1024);
  };
  auto brdf = [&](int b, int kk, int n) -> short8 {
    return *(const short8*)(BL + b * (BN * 128) + kk * (BN * 64) + boff + n * 1024);
  };

  auto compute = [&](int cb) {
    short8 bfr[NF], af[MF / 2];
#pragma unroll
    for (int kk = 0; kk < 2; ++kk) {
#pragma unroll
      for (int n = 0; n < NF; ++n) bfr[n] = brdf(cb, kk, n);
#pragma unroll
      for (int m = 0; m < MF / 2; ++m) af[m] = ardf(cb, kk, m);
      __builtin_amdgcn_s_setprio(1);
#pragma unroll
      for (int m = 0; m < MF / 2; ++m)
#pragma unroll
        for (int n = 0; n < NF; ++n)
          acc[m][n] = __builtin_amdgcn_mfma_f32_16x16x32_bf16(af[m], bfr[n], acc[m][n], 0, 0, 0);
      __builtin_amdgcn_s_setprio(0);
#pragma unroll
      for (int m = 0; m < MF / 2; ++m) af[m] = ardf(cb, kk, MF / 2 + m);
      __builtin_amdgcn_s_setprio(1);
#pragma unroll
      for (int m = 0; m < MF / 2; ++m)
#pragma unroll
        for (int n = 0; n < NF; ++n)
          acc[MF / 2 + m][n] =
              __builtin_amdgcn_mfma_f32_16x16x32_bf16(af[m], bfr[n], acc[MF / 2 + m][n], 0, 0, 0);
      __builtin_amdgcn_s_setprio(0);
    }
  };

  // prologue
  issueREG(0);                      // +R
  stageDMA(0, 0);                   // +D
  vmwait<D>();                      // REG(0) landed
  writeREG(0);
  if (nt > 1) issueREG(1);          // +R
  if (nt > 1) vmwait<R>(); else vmwait<0>();   // retire DMA(0)
  lgkm0(); barrier_();

  for (int u = 0; u < nt; ++u) {
    const int cb = u & 1, nb = cb ^ 1;
    if (u + 1 < nt) { stageDMA(nb, u + 1); vmwait<D>(); }  // REG(u+1) landed
    else            { vmwait<0>(); }
    if (u + 1 < nt) writeREG(nb);
    if (u + 2 < nt) issueREG(u + 2);
    compute(cb);
    if (u + 2 < nt)      vmwait<R>();   // retire DMA(u+1), keep REG(u+2)
    else                 vmwait<0>();
    lgkm0(); barrier_();
  }

  // epilogue: C/D layout col=lane&15, row=(lane>>4)*4+reg
#pragma unroll
  for (int m = 0; m < MF; ++m) {
    const int row = m0 + wr * (BM / 2) + m * 16 + fq * 4;
#pragma unroll
    for (int n = 0; n < NF; ++n) {
      const int col = n0 + wc * (BN / 4) + n * 16 + fr;
#pragma unroll
      for (int r = 0; r < 4; ++r)
        C[(long)(row + r) * ldc + col] = f2bf(acc[m][n][r]);
    }
  }
}

// Persistent Q/K + VT, conversion fused: 256 blocks.
// Phase 1: Q (id<128) or K projection, 256x256 tile, A = X f32 reg-staged.
// Phase 2: VT 128x256 half-tile, B = Xv f32 reg-staged.
__global__ __launch_bounds__(512, 2)
void qkvt_gemm(const float* __restrict__ Xq, const unsigned short* __restrict__ WQT,
               unsigned short* __restrict__ Q,
               const float* __restrict__ Xk, const unsigned short* __restrict__ WKT,
               unsigned short* __restrict__ Kk,
               const unsigned short* __restrict__ WVT, const float* __restrict__ Xv,
               unsigned short* __restrict__ VT) {
  __shared__ __align__(16) char pool[131072];
  const int id = (blockIdx.x & 7) * 32 + (blockIdx.x >> 3);   // 256 % 8 == 0
  const float* X = (id < 128) ? Xq : Xk;
  const unsigned short* W = (id < 128) ? WQT : WKT;
  unsigned short* Cc = (id < 128) ? Q : Kk;
  const int r = id & 127;
  gemm_fused<8, 4, false>(X, W, Cc, r >> 2, r & 3, 1024,
                          1024, 1024, 1024, pool, pool + 65536);
  __syncthreads();                              // drains vm+lgkm, LDS reusable
  gemm_fused<4, 4, true>(Xv, WVT, VT, id >> 5, id & 31, 1024,
                         1024, 1024, 8192, pool, pool + 32768);
}

// Scores: S_b = Q_b K_b^T; 128x128 tiles over the causal lower triangle.
// 4 batches x 136 lower-tri tiles = 544 blocks (2/CU): one round + tail.
__global__ __launch_bounds__(512, 4)
void scores_gemm(const unsigned short* __restrict__ Q, const unsigned short* __restrict__ K,
                 unsigned short* __restrict__ S) {
  __shared__ __align__(16) char pool[65536];
  const int gid = (blockIdx.x & 7) * 68 + (blockIdx.x >> 3);  // 544 = 8*68
  const int bz = gid / 136, t = gid - bz * 136;
  int bm = (int)((__fsqrt_rn(8.0f * t + 1.0f) - 1.0f) * 0.5f);
  while ((bm + 1) * (bm + 2) / 2 <= t) ++bm;
  while (bm * (bm + 1) / 2 > t) --bm;
  const int bn = t - bm * (bm + 1) / 2;
  gemm_body<unsigned short, 4, 2>(Q + (long)bz * 2048 * 1024, K + (long)bz * 2048 * 1024,
                                  S + (long)bz * 2048 * 2048, bm, bn, 1024,
                                  1024, 1024, 2048, pool, pool + 32768);
}

// PV: out_b = P_b V_b; 128x128 tiles (64 KiB LDS -> 2 blocks/CU).
// Heavy+light pairing: b<256 gets bm=15-(b>>5), b>=256 gets bm=(b-256)>>5.
__global__ __launch_bounds__(512, 4)
void pv_gemm(const unsigned short* __restrict__ P, const unsigned short* __restrict__ VT,
             float* __restrict__ O) {
  __shared__ __align__(16) char pool[65536];
  const int b = blockIdx.x;
  int bm, r;
  if (b < 256) { bm = 15 - (b >> 5); r = b & 31; }
  else         { bm = (b - 256) >> 5; r = b & 31; }
  const int bn = r & 7, bz = r >> 3;
  gemm_body<float, 4, 2>(P + (long)bz * 2048 * 2048, VT + (long)bz * 2048,
                         O + (long)bz * 2048 * 1024, bm, bn, (bm + 1) * 128,
                         2048, 8192, 1024, pool, pool + 32768);
}

// ---------------- causal softmax, vectorized, register-resident -------------
__global__ __launch_bounds__(256)
void softmax_causal(unsigned short* __restrict__ P) {
  const int row = blockIdx.x;              // b*2048 + q
  const int q = row & 2047;
  unsigned short* p = P + (long)row * 2048;
  const int nfill = ((q >> 7) + 1) << 7;   // PV reads up to this 128-boundary
  const int tid = threadIdx.x;
  const int lane = tid & 63, wid = tid >> 6;
  const int i0 = tid * 8;
  __shared__ float red[8];

  float v[8];
  float lmax = -3.0e38f;
  if (i0 <= q) {                           // skip loads past causal boundary
    ushort8 v8 = *(const ushort8*)(p + i0);
#pragma unroll
    for (int j = 0; j < 8; ++j) {
      float f = bf2f(v8[j]);
      f = (i0 + j <= q) ? f : -3.0e38f;
      v[j] = f;
      lmax = fmaxf(lmax, f);
    }
  } else {
#pragma unroll
    for (int j = 0; j < 8; ++j) v[j] = -3.0e38f;
  }
#pragma unroll
  for (int off = 1; off < 64; off <<= 1)
    lmax = fmaxf(lmax, __shfl_xor(lmax, off));
  if (lane == 0) red[wid] = lmax;
  __syncthreads();
  const float mx = fmaxf(fmaxf(red[0], red[1]), fmaxf(red[2], red[3]));

  float lsum = 0.f;
#pragma unroll
  for (int j = 0; j < 8; ++j) {
    float e = __expf(v[j] - mx);           // masked lanes -> exp(-huge) = 0
    v[j] = e;
    lsum += e;
  }
#pragma unroll
  for (int off = 1; off < 64; off <<= 1)
    lsum += __shfl_xor(lsum, off);
  if (lane == 0) red[4 + wid] = lsum;
  __syncthreads();
  const float inv = 1.0f / (red[4] + red[5] + red[6] + red[7]);

  if (i0 < nfill) {
    ushort8 r;
#pragma unroll
    for (int j = 0; j < 8; ++j)
      r[j] = (i0 + j <= q) ? f2bf(v[j] * inv) : (unsigned short)0;
    *(ushort8*)(p + i0) = r;
  }
}

// ---------------------------------------------------------------------------
extern "C" void kernel_launch(void* const* d_in, const int* in_sizes, int n_in,
                              void* d_out, int out_size, void* d_ws, size_t ws_size,
                              hipStream_t stream) {
  const float* Xk = (const float*)d_in[0];
  const float* Xv = (const float*)d_in[1];
  const float* Xq = (const float*)d_in[2];
  const float* WK = (const float*)d_in[3];
  const float* WQ = (const float*)d_in[4];
  const float* WV = (const float*)d_in[5];
  float* out = (float*)d_out;

  unsigned short* ws = (unsigned short*)d_ws;
  const long NE = 8L * 1024 * 1024;          // 8192*1024 elems
  unsigned short* Sc  = ws;                  // 2*NE elems (scores/P)
  unsigned short* Qb  = ws + 2 * NE;
  unsigned short* Kb  = ws + 3 * NE;
  unsigned short* VTb = ws + 4 * NE;
  unsigned short* WQT = ws + 5 * NE;
  unsigned short* WKT = WQT + 1024 * 1024;
  unsigned short* WVT = WKT + 1024 * 1024;

  dim3 b256(256), b512(512);
  wtrans3<<<dim3(32, 32, 3), dim3(32, 8), 0, stream>>>(WQ, WK, WV, WQT, WKT, WVT);
  qkvt_gemm<<<256, b512, 0, stream>>>(Xq, WQT, Qb, Xk, WKT, Kb, WVT, Xv, VTb);
  scores_gemm<<<544, b512, 0, stream>>>(Qb, Kb, Sc);
  softmax_causal<<<8192, b256, 0, stream>>>(Sc);
  pv_gemm<<<512, b512, 0, stream>>>(Sc, VTb, out);
}

// Round 10
// 163.032 us; speedup vs baseline: 1.0180x; 1.0180x over previous
//
#include <hip/hip_runtime.h>
#include <stdint.h>

// ---------------------------------------------------------------------------
// AttentionHead: out = softmax_causal((Xq WQ)(Xk WK)^T / sqrt(D)) (Xv WV)
// B=4, S=2048, D=1024.  bf16 MFMA 16x16x32, f32 accumulate.
// Round 10: r5-best config restored (separate cvt, bf16 GEMM inputs) with a
// simplified K-loop: FULL-TILE residency — per K-tile {lgkm0; bar; stage
// tile u+1 (S loads); vmwait<S>; bar; 64 MFMA uninterrupted}.  One vmwait,
// two barriers per K-tile (r5 had 2 vmwaits + 3 barriers).  cvt+wtrans in
// one prep dispatch.
// ---------------------------------------------------------------------------

typedef __attribute__((ext_vector_type(8))) short short8;
typedef __attribute__((ext_vector_type(8))) unsigned short ushort8;
typedef __attribute__((ext_vector_type(4))) float f32x4;

__device__ __forceinline__ unsigned short f2bf(float f) {
  union { float f; unsigned u; } v; v.f = f;
  unsigned u = v.u + 0x7FFFu + ((v.u >> 16) & 1u);   // RNE
  return (unsigned short)(u >> 16);
}
__device__ __forceinline__ float bf2f(unsigned short h) {
  union { unsigned u; float f; } v; v.u = ((unsigned)h) << 16;
  return v.f;
}

__device__ __forceinline__ void gload16(const void* g, void* l) {
  __builtin_amdgcn_global_load_lds(
      (const __attribute__((address_space(1))) unsigned int*)g,
      (__attribute__((address_space(3))) unsigned int*)l, 16, 0, 0);
}

template<int N> __device__ __forceinline__ void vmwait() {
  static_assert(N >= 0 && N <= 8, "vmcnt range");
  if constexpr (N == 0) asm volatile("s_waitcnt vmcnt(0)" ::: "memory");
  else if constexpr (N == 1) asm volatile("s_waitcnt vmcnt(1)" ::: "memory");
  else if constexpr (N == 2) asm volatile("s_waitcnt vmcnt(2)" ::: "memory");
  else if constexpr (N == 3) asm volatile("s_waitcnt vmcnt(3)" ::: "memory");
  else if constexpr (N == 4) asm volatile("s_waitcnt vmcnt(4)" ::: "memory");
  else if constexpr (N == 5) asm volatile("s_waitcnt vmcnt(5)" ::: "memory");
  else if constexpr (N == 6) asm volatile("s_waitcnt vmcnt(6)" ::: "memory");
  else if constexpr (N == 7) asm volatile("s_waitcnt vmcnt(7)" ::: "memory");
  else asm volatile("s_waitcnt vmcnt(8)" ::: "memory");
}
__device__ __forceinline__ void barrier_() { asm volatile("s_barrier" ::: "memory"); }
__device__ __forceinline__ void lgkm0() { asm volatile("s_waitcnt lgkmcnt(0)" ::: "memory"); }

// ---------------- prep: cvt x3 tensors + weight transpose x3, one dispatch --
__global__ __launch_bounds__(256)
void prep(const float* __restrict__ Xq, const float* __restrict__ Xk,
          const float* __restrict__ Xv,
          unsigned short* __restrict__ Oq, unsigned short* __restrict__ Ok,
          unsigned short* __restrict__ Ov,
          const float* __restrict__ WQ, const float* __restrict__ WK,
          const float* __restrict__ WV,
          unsigned short* __restrict__ WQT, unsigned short* __restrict__ WKT,
          unsigned short* __restrict__ WVT) {
  const int bx = blockIdx.x;
  const int tid = threadIdx.x;
  if (bx < 12288) {                                // cvt: 4096 blocks/tensor
    const int op = bx >> 12, r = bx & 4095;
    const float* in = op == 0 ? Xq : op == 1 ? Xk : Xv;
    unsigned short* out = op == 0 ? Oq : op == 1 ? Ok : Ov;
    const long i = ((long)r * 256 + tid) * 8;
    float4 a = *(const float4*)(in + i);
    float4 b = *(const float4*)(in + i + 4);
    ushort8 rr;
    rr[0] = f2bf(a.x); rr[1] = f2bf(a.y); rr[2] = f2bf(a.z); rr[3] = f2bf(a.w);
    rr[4] = f2bf(b.x); rr[5] = f2bf(b.y); rr[6] = f2bf(b.z); rr[7] = f2bf(b.w);
    *(ushort8*)(out + i) = rr;
  } else {                                         // wtrans: 1024 blocks/tensor
    const int t = bx - 12288;
    const int z = t >> 10, rem = t & 1023;
    const float* W = z == 0 ? WQ : z == 1 ? WK : WV;
    unsigned short* WT = z == 0 ? WQT : z == 1 ? WKT : WVT;
    const float scale = z == 0 ? 0.03125f : 1.0f;  // 1/sqrt(1024) into WQT
    __shared__ float tbuf[32][33];
    const int bk = (rem >> 5) * 32, be = (rem & 31) * 32;
    const int tx = tid & 31, ty = tid >> 5;        // (32,8)
#pragma unroll
    for (int j = 0; j < 32; j += 8)
      tbuf[ty + j][tx] = W[(long)(bk + ty + j) * 1024 + (be + tx)];
    __syncthreads();
#pragma unroll
    for (int j = 0; j < 32; j += 8)
      WT[(long)(be + ty + j) * 1024 + (bk + tx)] = f2bf(tbuf[tx][ty + j] * scale);
  }
}

// ---------------- B^T-layout bf16 GEMM, full-tile-residency K-loop ----------
// C[m][n] = sum_k A[m][k]*B[n][k].  BM=MF*32, BN=NF*64.  8 waves (2Mx4N).
// LDS [buf][khalf][row][32]; 16B-slot swizzle ^((row>>1)&3)  (0-conflict, r5).
// Ledger: entering iter u outstanding=S (tile u); +S; vmwait<S> retires tile u.
template<typename CT, int MF, int NF>
__device__ __forceinline__ void gemm_body(const unsigned short* __restrict__ A,
                                          const unsigned short* __restrict__ B,
                                          CT* __restrict__ C,
                                          int bm, int bn, int kmax,
                                          int lda, int ldb, int ldc,
                                          char* AL, char* BL) {
  constexpr int BM = MF * 32, BN = NF * 64;
  constexpr int LA = BM / 128, LB = BN / 128;      // gloads per k-half
  constexpr int S = 2 * (LA + LB);                 // gloads per K-tile

  const int tid = threadIdx.x;                     // 0..511
  const int lane = tid & 63, wid = tid >> 6;
  const int wr = wid >> 2, wc = wid & 3;           // 2x4 wave grid
  const int fr = lane & 15, fq = lane >> 4;
  const int srow = tid >> 2;                       // staging row 0..127
  const int scol = (((tid & 3) ^ ((tid >> 3) & 3)) << 3);  // pre-swz src col
  const int m0 = bm * BM, n0 = bn * BN;
  const int nt = kmax >> 6;

  f32x4 acc[MF][NF] = {};

  const unsigned short* As = A + (long)(m0 + srow) * lda + scol;
  const unsigned short* Bs = B + (long)(n0 + srow) * ldb + scol;

  auto stageTile = [&](int b, int kt) {            // whole K-tile kt -> buf b
#pragma unroll
    for (int h = 0; h < 2; ++h) {
#pragma unroll
      for (int l = 0; l < LA; ++l)
        gload16(As + (long)l * 128 * lda + kt * 64 + h * 32,
                AL + b * (BM * 128) + h * (BM * 64) + l * 8192 + tid * 16);
#pragma unroll
      for (int l = 0; l < LB; ++l)
        gload16(Bs + (long)l * 128 * ldb + kt * 64 + h * 32,
                BL + b * (BN * 128) + h * (BN * 64) + l * 8192 + tid * 16);
    }
  };

  const int aoff = (wr * (BM / 2) + fr) * 64 + ((fq ^ ((fr >> 1) & 3)) << 4);
  const int boff = (wc * (BN / 4) + fr) * 64 + ((fq ^ ((fr >> 1) & 3)) << 4);
  auto ardf = [&](int b, int kk, int m) -> short8 {
    return *(const short8*)(AL + b * (BM * 128) + kk * (BM * 64) + aoff + m * 1024);
  };
  auto brdf = [&](int b, int kk, int n) -> short8 {
    return *(const short8*)(BL + b * (BN * 128) + kk * (BN * 64) + boff + n * 1024);
  };

  stageTile(0, 0);                                 // prologue: tile 0 -> buf 0

  for (int u = 0; u < nt; ++u) {
    const int cb = u & 1, nb = cb ^ 1;
    lgkm0();                                   // my ds_reads of buf nb serviced
    barrier_();                                // all waves done reading buf nb
    if (u + 1 < nt) { stageTile(nb, u + 1); vmwait<S>(); }  // retire tile u
    else            { vmwait<0>(); }
    barrier_();                                // tile u resident for all waves
    // 4 MFMA clusters, no further syncs — compiler free to pipeline reads.
#pragma unroll
    for (int kk = 0; kk < 2; ++kk) {
      short8 bfr[NF], af[MF / 2];
#pragma unroll
      for (int n = 0; n < NF; ++n) bfr[n] = brdf(cb, kk, n);
#pragma unroll
      for (int m = 0; m < MF / 2; ++m) af[m] = ardf(cb, kk, m);
      __builtin_amdgcn_s_setprio(1);
#pragma unroll
      for (int m = 0; m < MF / 2; ++m)
#pragma unroll
        for (int n = 0; n < NF; ++n)
          acc[m][n] = __builtin_amdgcn_mfma_f32_16x16x32_bf16(af[m], bfr[n], acc[m][n], 0, 0, 0);
      __builtin_amdgcn_s_setprio(0);
#pragma unroll
      for (int m = 0; m < MF / 2; ++m) af[m] = ardf(cb, kk, MF / 2 + m);
      __builtin_amdgcn_s_setprio(1);
#pragma unroll
      for (int m = 0; m < MF / 2; ++m)
#pragma unroll
        for (int n = 0; n < NF; ++n)
          acc[MF / 2 + m][n] =
              __builtin_amdgcn_mfma_f32_16x16x32_bf16(af[m], bfr[n], acc[MF / 2 + m][n], 0, 0, 0);
      __builtin_amdgcn_s_setprio(0);
    }
  }

  // C/D layout: col = lane&15, row = (lane>>4)*4 + reg
#pragma unroll
  for (int m = 0; m < MF; ++m) {
    const int row = m0 + wr * (BM / 2) + m * 16 + fq * 4;
#pragma unroll
    for (int n = 0; n < NF; ++n) {
      const int col = n0 + wc * (BN / 4) + n * 16 + fr;
#pragma unroll
      for (int r = 0; r < 4; ++r) {
        float v = acc[m][n][r];
        if constexpr (sizeof(CT) == 2)
          C[(long)(row + r) * ldc + col] = (CT)f2bf(v);
        else
          C[(long)(row + r) * ldc + col] = (CT)v;
      }
    }
  }
}

// Persistent Q/K + VT: 256 blocks.  Each block: one 256^2 Q-or-K tile
// (K=1024), then one 128x256 VT half-tile.  1.5 T_block each, no tail.
__global__ __launch_bounds__(512, 2)
void qkvt_gemm(const unsigned short* __restrict__ Xq, const unsigned short* __restrict__ WQT,
               unsigned short* __restrict__ Q,
               const unsigned short* __restrict__ Xk, const unsigned short* __restrict__ WKT,
               unsigned short* __restrict__ Kk,
               const unsigned short* __restrict__ WVT, const unsigned short* __restrict__ Xv,
               unsigned short* __restrict__ VT) {
  __shared__ __align__(16) char pool[131072];
  const int id = (blockIdx.x & 7) * 32 + (blockIdx.x >> 3);   // 256 % 8 == 0
  if (id < 128)
    gemm_body<unsigned short, 8, 4>(Xq, WQT, Q, id >> 2, id & 3, 1024,
                                    1024, 1024, 1024, pool, pool + 65536);
  else
    gemm_body<unsigned short, 8, 4>(Xk, WKT, Kk, (id - 128) >> 2, id & 3, 1024,
                                    1024, 1024, 1024, pool, pool + 65536);
  __syncthreads();                              // LDS safe to reuse
  gemm_body<unsigned short, 4, 4>(WVT, Xv, VT, id >> 5, id & 31, 1024,
                                  1024, 1024, 8192, pool, pool + 32768);
}

// Scores: S_b = Q_b K_b^T; 128x128 tiles over the causal lower triangle.
// 4 batches x 136 lower-tri tiles = 544 blocks (2/CU): one round + tail.
__global__ __launch_bounds__(512, 4)
void scores_gemm(const unsigned short* __restrict__ Q, const unsigned short* __restrict__ K,
                 unsigned short* __restrict__ S) {
  __shared__ __align__(16) char pool[65536];
  const int gid = (blockIdx.x & 7) * 68 + (blockIdx.x >> 3);  // 544 = 8*68
  const int bz = gid / 136, t = gid - bz * 136;
  int bm = (int)((__fsqrt_rn(8.0f * t + 1.0f) - 1.0f) * 0.5f);
  while ((bm + 1) * (bm + 2) / 2 <= t) ++bm;
  while (bm * (bm + 1) / 2 > t) --bm;
  const int bn = t - bm * (bm + 1) / 2;
  gemm_body<unsigned short, 4, 2>(Q + (long)bz * 2048 * 1024, K + (long)bz * 2048 * 1024,
                                  S + (long)bz * 2048 * 2048, bm, bn, 1024,
                                  1024, 1024, 2048, pool, pool + 32768);
}

// PV: out_b = P_b V_b; 128x128 tiles (64 KiB LDS -> 2 blocks/CU).
// Heavy+light pairing: b<256 gets bm=15-(b>>5), b>=256 gets bm=(b-256)>>5.
__global__ __launch_bounds__(512, 4)
void pv_gemm(const unsigned short* __restrict__ P, const unsigned short* __restrict__ VT,
             float* __restrict__ O) {
  __shared__ __align__(16) char pool[65536];
  const int b = blockIdx.x;
  int bm, r;
  if (b < 256) { bm = 15 - (b >> 5); r = b & 31; }
  else         { bm = (b - 256) >> 5; r = b & 31; }
  const int bn = r & 7, bz = r >> 3;
  gemm_body<float, 4, 2>(P + (long)bz * 2048 * 2048, VT + (long)bz * 2048,
                         O + (long)bz * 2048 * 1024, bm, bn, (bm + 1) * 128,
                         2048, 8192, 1024, pool, pool + 32768);
}

// ---------------- causal softmax, vectorized, register-resident -------------
__global__ __launch_bounds__(256)
void softmax_causal(unsigned short* __restrict__ P) {
  const int row = blockIdx.x;              // b*2048 + q
  const int q = row & 2047;
  unsigned short* p = P + (long)row * 2048;
  const int nfill = ((q >> 7) + 1) << 7;   // PV reads up to this 128-boundary
  const int tid = threadIdx.x;
  const int lane = tid & 63, wid = tid >> 6;
  const int i0 = tid * 8;
  __shared__ float red[8];

  float v[8];
  float lmax = -3.0e38f;
  if (i0 <= q) {                           // skip loads past causal boundary
    ushort8 v8 = *(const ushort8*)(p + i0);
#pragma unroll
    for (int j = 0; j < 8; ++j) {
      float f = bf2f(v8[j]);
      f = (i0 + j <= q) ? f : -3.0e38f;
      v[j] = f;
      lmax = fmaxf(lmax, f);
    }
  } else {
#pragma unroll
    for (int j = 0; j < 8; ++j) v[j] = -3.0e38f;
  }
#pragma unroll
  for (int off = 1; off < 64; off <<= 1)
    lmax = fmaxf(lmax, __shfl_xor(lmax, off));
  if (lane == 0) red[wid] = lmax;
  __syncthreads();
  const float mx = fmaxf(fmaxf(red[0], red[1]), fmaxf(red[2], red[3]));

  float lsum = 0.f;
#pragma unroll
  for (int j = 0; j < 8; ++j) {
    float e = __expf(v[j] - mx);           // masked lanes -> exp(-huge) = 0
    v[j] = e;
    lsum += e;
  }
#pragma unroll
  for (int off = 1; off < 64; off <<= 1)
    lsum += __shfl_xor(lsum, off);
  if (lane == 0) red[4 + wid] = lsum;
  __syncthreads();
  const float inv = 1.0f / (red[4] + red[5] + red[6] + red[7]);

  if (i0 < nfill) {
    ushort8 r;
#pragma unroll
    for (int j = 0; j < 8; ++j)
      r[j] = (i0 + j <= q) ? f2bf(v[j] * inv) : (unsigned short)0;
    *(ushort8*)(p + i0) = r;
  }
}

// ---------------------------------------------------------------------------
extern "C" void kernel_launch(void* const* d_in, const int* in_sizes, int n_in,
                              void* d_out, int out_size, void* d_ws, size_t ws_size,
                              hipStream_t stream) {
  const float* Xk = (const float*)d_in[0];
  const float* Xv = (const float*)d_in[1];
  const float* Xq = (const float*)d_in[2];
  const float* WK = (const float*)d_in[3];
  const float* WQ = (const float*)d_in[4];
  const float* WV = (const float*)d_in[5];
  float* out = (float*)d_out;

  unsigned short* ws = (unsigned short*)d_ws;
  const long NE = 8L * 1024 * 1024;          // 8192*1024 elems
  unsigned short* Xqb = ws + 0 * NE;
  unsigned short* Xkb = ws + 1 * NE;
  unsigned short* Xvb = ws + 2 * NE;
  unsigned short* Qb  = ws + 3 * NE;
  unsigned short* Kb  = ws + 4 * NE;
  unsigned short* VTb = ws + 5 * NE;
  unsigned short* WQT = ws + 6 * NE;
  unsigned short* WKT = WQT + 1024 * 1024;
  unsigned short* WVT = WKT + 1024 * 1024;
  unsigned short* Sc  = ws;                  // 2^24 elems, aliases dead Xq+Xk

  dim3 b256(256), b512(512);
  prep<<<15360, b256, 0, stream>>>(Xq, Xk, Xv, Xqb, Xkb, Xvb,
                                   WQ, WK, WV, WQT, WKT, WVT);
  qkvt_gemm<<<256, b512, 0, stream>>>(Xqb, WQT, Qb, Xkb, WKT, Kb, WVT, Xvb, VTb);
  scores_gemm<<<544, b512, 0, stream>>>(Qb, Kb, Sc);
  softmax_causal<<<8192, b256, 0, stream>>>(Sc);
  pv_gemm<<<512, b512, 0, stream>>>(Sc, VTb, out);
}

// Round 11
// 158.185 us; speedup vs baseline: 1.0492x; 1.0306x over previous
//
#include <hip/hip_runtime.h>
#include <stdint.h>

// ---------------------------------------------------------------------------
// AttentionHead: out = softmax_causal((Xq WQ)(Xk WK)^T / sqrt(D)) (Xv WV)
// B=4, S=2048, D=1024.  bf16 MFMA 16x16x32, f32 accumulate.
// Round 11: m201-style 4-phase K-loop for qkvt:
//   boundary: [stage A-k0(u+1)] [vmwait<LA>] [barrier: tile-u resident]
//   phase p:  [ds_read this phase's frags] [stage 1 pair] [barrier]
//             [setprio 1; MFMA cluster; setprio 0] [barrier]
//   24 ds_read_b128 / K-tile (minimal), reads always pre-barrier, gloads
//   2-per-phase, one counted vmwait per K-tile.  scores/pv keep r10 body.
// ---------------------------------------------------------------------------

typedef __attribute__((ext_vector_type(8))) short short8;
typedef __attribute__((ext_vector_type(8))) unsigned short ushort8;
typedef __attribute__((ext_vector_type(4))) float f32x4;

__device__ __forceinline__ unsigned short f2bf(float f) {
  union { float f; unsigned u; } v; v.f = f;
  unsigned u = v.u + 0x7FFFu + ((v.u >> 16) & 1u);   // RNE
  return (unsigned short)(u >> 16);
}
__device__ __forceinline__ float bf2f(unsigned short h) {
  union { unsigned u; float f; } v; v.u = ((unsigned)h) << 16;
  return v.f;
}

__device__ __forceinline__ void gload16(const void* g, void* l) {
  __builtin_amdgcn_global_load_lds(
      (const __attribute__((address_space(1))) unsigned int*)g,
      (__attribute__((address_space(3))) unsigned int*)l, 16, 0, 0);
}

template<int N> __device__ __forceinline__ void vmwait() {
  static_assert(N >= 0 && N <= 8, "vmcnt range");
  if constexpr (N == 0) asm volatile("s_waitcnt vmcnt(0)" ::: "memory");
  else if constexpr (N == 1) asm volatile("s_waitcnt vmcnt(1)" ::: "memory");
  else if constexpr (N == 2) asm volatile("s_waitcnt vmcnt(2)" ::: "memory");
  else if constexpr (N == 3) asm volatile("s_waitcnt vmcnt(3)" ::: "memory");
  else if constexpr (N == 4) asm volatile("s_waitcnt vmcnt(4)" ::: "memory");
  else if constexpr (N == 5) asm volatile("s_waitcnt vmcnt(5)" ::: "memory");
  else if constexpr (N == 6) asm volatile("s_waitcnt vmcnt(6)" ::: "memory");
  else if constexpr (N == 7) asm volatile("s_waitcnt vmcnt(7)" ::: "memory");
  else asm volatile("s_waitcnt vmcnt(8)" ::: "memory");
}
__device__ __forceinline__ void barrier_() { asm volatile("s_barrier" ::: "memory"); }
__device__ __forceinline__ void lgkm0() { asm volatile("s_waitcnt lgkmcnt(0)" ::: "memory"); }

// ---------------- prep: cvt x3 tensors + weight transpose x3, one dispatch --
__global__ __launch_bounds__(256)
void prep(const float* __restrict__ Xq, const float* __restrict__ Xk,
          const float* __restrict__ Xv,
          unsigned short* __restrict__ Oq, unsigned short* __restrict__ Ok,
          unsigned short* __restrict__ Ov,
          const float* __restrict__ WQ, const float* __restrict__ WK,
          const float* __restrict__ WV,
          unsigned short* __restrict__ WQT, unsigned short* __restrict__ WKT,
          unsigned short* __restrict__ WVT) {
  const int bx = blockIdx.x;
  const int tid = threadIdx.x;
  if (bx < 12288) {                                // cvt: 4096 blocks/tensor
    const int op = bx >> 12, r = bx & 4095;
    const float* in = op == 0 ? Xq : op == 1 ? Xk : Xv;
    unsigned short* out = op == 0 ? Oq : op == 1 ? Ok : Ov;
    const long i = ((long)r * 256 + tid) * 8;
    float4 a = *(const float4*)(in + i);
    float4 b = *(const float4*)(in + i + 4);
    ushort8 rr;
    rr[0] = f2bf(a.x); rr[1] = f2bf(a.y); rr[2] = f2bf(a.z); rr[3] = f2bf(a.w);
    rr[4] = f2bf(b.x); rr[5] = f2bf(b.y); rr[6] = f2bf(b.z); rr[7] = f2bf(b.w);
    *(ushort8*)(out + i) = rr;
  } else {                                         // wtrans: 1024 blocks/tensor
    const int t = bx - 12288;
    const int z = t >> 10, rem = t & 1023;
    const float* W = z == 0 ? WQ : z == 1 ? WK : WV;
    unsigned short* WT = z == 0 ? WQT : z == 1 ? WKT : WVT;
    const float scale = z == 0 ? 0.03125f : 1.0f;  // 1/sqrt(1024) into WQT
    __shared__ float tbuf[32][33];
    const int bk = (rem >> 5) * 32, be = (rem & 31) * 32;
    const int tx = tid & 31, ty = tid >> 5;        // (32,8)
#pragma unroll
    for (int j = 0; j < 32; j += 8)
      tbuf[ty + j][tx] = W[(long)(bk + ty + j) * 1024 + (be + tx)];
    __syncthreads();
#pragma unroll
    for (int j = 0; j < 32; j += 8)
      WT[(long)(be + ty + j) * 1024 + (bk + tx)] = f2bf(tbuf[tx][ty + j] * scale);
  }
}

// ================= shared layout helpers (both GEMM bodies) =================
// LDS [buf][khalf][row][32 cols bf16]; 16B-slot swizzle ^((row>>1)&3).

// ---------------- body A: r10 full-tile-residency loop (scores/pv) ----------
template<typename CT, int MF, int NF>
__device__ __forceinline__ void gemm_body(const unsigned short* __restrict__ A,
                                          const unsigned short* __restrict__ B,
                                          CT* __restrict__ C,
                                          int bm, int bn, int kmax,
                                          int lda, int ldb, int ldc,
                                          char* AL, char* BL) {
  constexpr int BM = MF * 32, BN = NF * 64;
  constexpr int LA = BM / 128, LB = BN / 128;
  constexpr int S = 2 * (LA + LB);

  const int tid = threadIdx.x;
  const int lane = tid & 63, wid = tid >> 6;
  const int wr = wid >> 2, wc = wid & 3;
  const int fr = lane & 15, fq = lane >> 4;
  const int srow = tid >> 2;
  const int scol = (((tid & 3) ^ ((tid >> 3) & 3)) << 3);
  const int m0 = bm * BM, n0 = bn * BN;
  const int nt = kmax >> 6;

  f32x4 acc[MF][NF] = {};

  const unsigned short* As = A + (long)(m0 + srow) * lda + scol;
  const unsigned short* Bs = B + (long)(n0 + srow) * ldb + scol;

  auto stageTile = [&](int b, int kt) {
#pragma unroll
    for (int h = 0; h < 2; ++h) {
#pragma unroll
      for (int l = 0; l < LA; ++l)
        gload16(As + (long)l * 128 * lda + kt * 64 + h * 32,
                AL + b * (BM * 128) + h * (BM * 64) + l * 8192 + tid * 16);
#pragma unroll
      for (int l = 0; l < LB; ++l)
        gload16(Bs + (long)l * 128 * ldb + kt * 64 + h * 32,
                BL + b * (BN * 128) + h * (BN * 64) + l * 8192 + tid * 16);
    }
  };

  const int aoff = (wr * (BM / 2) + fr) * 64 + ((fq ^ ((fr >> 1) & 3)) << 4);
  const int boff = (wc * (BN / 4) + fr) * 64 + ((fq ^ ((fr >> 1) & 3)) << 4);
  auto ardf = [&](int b, int kk, int m) -> short8 {
    return *(const short8*)(AL + b * (BM * 128) + kk * (BM * 64) + aoff + m * 1024);
  };
  auto brdf = [&](int b, int kk, int n) -> short8 {
    return *(const short8*)(BL + b * (BN * 128) + kk * (BN * 64) + boff + n * 1024);
  };

  stageTile(0, 0);

  for (int u = 0; u < nt; ++u) {
    const int cb = u & 1, nb = cb ^ 1;
    lgkm0();
    barrier_();
    if (u + 1 < nt) { stageTile(nb, u + 1); vmwait<S>(); }
    else            { vmwait<0>(); }
    barrier_();
#pragma unroll
    for (int kk = 0; kk < 2; ++kk) {
      short8 bfr[NF], af[MF / 2];
#pragma unroll
      for (int n = 0; n < NF; ++n) bfr[n] = brdf(cb, kk, n);
#pragma unroll
      for (int m = 0; m < MF / 2; ++m) af[m] = ardf(cb, kk, m);
      __builtin_amdgcn_s_setprio(1);
#pragma unroll
      for (int m = 0; m < MF / 2; ++m)
#pragma unroll
        for (int n = 0; n < NF; ++n)
          acc[m][n] = __builtin_amdgcn_mfma_f32_16x16x32_bf16(af[m], bfr[n], acc[m][n], 0, 0, 0);
      __builtin_amdgcn_s_setprio(0);
#pragma unroll
      for (int m = 0; m < MF / 2; ++m) af[m] = ardf(cb, kk, MF / 2 + m);
      __builtin_amdgcn_s_setprio(1);
#pragma unroll
      for (int m = 0; m < MF / 2; ++m)
#pragma unroll
        for (int n = 0; n < NF; ++n)
          acc[MF / 2 + m][n] =
              __builtin_amdgcn_mfma_f32_16x16x32_bf16(af[m], bfr[n], acc[MF / 2 + m][n], 0, 0, 0);
      __builtin_amdgcn_s_setprio(0);
    }
  }

#pragma unroll
  for (int m = 0; m < MF; ++m) {
    const int row = m0 + wr * (BM / 2) + m * 16 + fq * 4;
#pragma unroll
    for (int n = 0; n < NF; ++n) {
      const int col = n0 + wc * (BN / 4) + n * 16 + fr;
#pragma unroll
      for (int r = 0; r < 4; ++r) {
        float v = acc[m][n][r];
        if constexpr (sizeof(CT) == 2)
          C[(long)(row + r) * ldc + col] = (CT)f2bf(v);
        else
          C[(long)(row + r) * ldc + col] = (CT)v;
      }
    }
  }
}

// ---------------- body B: m201-style 4-phase loop (qkvt) --------------------
// Phases per K-tile u (buf cb), 24 ds_read_b128 total:
//   ph0 (kk0): read B[0][*]+A[0][lo];  stage B-k0(u+1); bar; MFMA lo; bar
//   ph1 (kk0): read A[0][hi];          stage A-k1(u+1); bar; MFMA hi; bar
//   ph2 (kk1): read B[1][*]+A[1][lo];  stage B-k1(u+1); bar; MFMA lo; bar
//   ph3 (kk1): read A[1][hi];          (no stage)       bar; MFMA hi; bar
// Boundary: stage A-k0(u+1); vmwait<LA> (retire tile u); bar (residency).
template<int MF, int NF>
__device__ __forceinline__ void gemm_4ph(const unsigned short* __restrict__ A,
                                         const unsigned short* __restrict__ B,
                                         unsigned short* __restrict__ C,
                                         int bm, int bn, int kmax,
                                         int lda, int ldb, int ldc,
                                         char* AL, char* BL) {
  constexpr int BM = MF * 32, BN = NF * 64;
  constexpr int LA = BM / 128, LB = BN / 128;

  const int tid = threadIdx.x;
  const int lane = tid & 63, wid = tid >> 6;
  const int wr = wid >> 2, wc = wid & 3;
  const int fr = lane & 15, fq = lane >> 4;
  const int srow = tid >> 2;
  const int scol = (((tid & 3) ^ ((tid >> 3) & 3)) << 3);
  const int m0 = bm * BM, n0 = bn * BN;
  const int nt = kmax >> 6;

  f32x4 acc[MF][NF] = {};

  const unsigned short* As = A + (long)(m0 + srow) * lda + scol;
  const unsigned short* Bs = B + (long)(n0 + srow) * ldb + scol;

  auto stageA = [&](int b, int h, int kt) {
#pragma unroll
    for (int l = 0; l < LA; ++l)
      gload16(As + (long)l * 128 * lda + kt * 64 + h * 32,
              AL + b * (BM * 128) + h * (BM * 64) + l * 8192 + tid * 16);
  };
  auto stageB = [&](int b, int h, int kt) {
#pragma unroll
    for (int l = 0; l < LB; ++l)
      gload16(Bs + (long)l * 128 * ldb + kt * 64 + h * 32,
              BL + b * (BN * 128) + h * (BN * 64) + l * 8192 + tid * 16);
  };

  const int aoff = (wr * (BM / 2) + fr) * 64 + ((fq ^ ((fr >> 1) & 3)) << 4);
  const int boff = (wc * (BN / 4) + fr) * 64 + ((fq ^ ((fr >> 1) & 3)) << 4);
  auto ardf = [&](int b, int kk, int m) -> short8 {
    return *(const short8*)(AL + b * (BM * 128) + kk * (BM * 64) + aoff + m * 1024);
  };
  auto brdf = [&](int b, int kk, int n) -> short8 {
    return *(const short8*)(BL + b * (BN * 128) + kk * (BN * 64) + boff + n * 1024);
  };

  // prologue: tile 0 -> buf 0  (A-k0, B-k0, A-k1, B-k1)
  stageA(0, 0, 0); stageB(0, 0, 0); stageA(0, 1, 0); stageB(0, 1, 0);

  short8 bfr[NF], af[MF / 2];
  for (int u = 0; u < nt; ++u) {
    const int cb = u & 1, nb = cb ^ 1;
    const bool pf = (u + 1 < nt);
    // ---- residency boundary: retire tile u across all waves
    if (pf) { stageA(nb, 0, u + 1); vmwait<LA>(); }
    else    { vmwait<0>(); }
    barrier_();
    // ---- phase 0: kk=0, lo half
#pragma unroll
    for (int n = 0; n < NF; ++n) bfr[n] = brdf(cb, 0, n);
#pragma unroll
    for (int m = 0; m < MF / 2; ++m) af[m] = ardf(cb, 0, m);
    if (pf) stageB(nb, 0, u + 1);
    barrier_();
    __builtin_amdgcn_s_setprio(1);
#pragma unroll
    for (int m = 0; m < MF / 2; ++m)
#pragma unroll
      for (int n = 0; n < NF; ++n)
        acc[m][n] = __builtin_amdgcn_mfma_f32_16x16x32_bf16(af[m], bfr[n], acc[m][n], 0, 0, 0);
    __builtin_amdgcn_s_setprio(0);
    barrier_();
    // ---- phase 1: kk=0, hi half
#pragma unroll
    for (int m = 0; m < MF / 2; ++m) af[m] = ardf(cb, 0, MF / 2 + m);
    if (pf) stageA(nb, 1, u + 1);
    barrier_();
    __builtin_amdgcn_s_setprio(1);
#pragma unroll
    for (int m = 0; m < MF / 2; ++m)
#pragma unroll
      for (int n = 0; n < NF; ++n)
        acc[MF / 2 + m][n] =
            __builtin_amdgcn_mfma_f32_16x16x32_bf16(af[m], bfr[n], acc[MF / 2 + m][n], 0, 0, 0);
    __builtin_amdgcn_s_setprio(0);
    barrier_();
    // ---- phase 2: kk=1, lo half
#pragma unroll
    for (int n = 0; n < NF; ++n) bfr[n] = brdf(cb, 1, n);
#pragma unroll
    for (int m = 0; m < MF / 2; ++m) af[m] = ardf(cb, 1, m);
    if (pf) stageB(nb, 1, u + 1);
    barrier_();
    __builtin_amdgcn_s_setprio(1);
#pragma unroll
    for (int m = 0; m < MF / 2; ++m)
#pragma unroll
      for (int n = 0; n < NF; ++n)
        acc[m][n] = __builtin_amdgcn_mfma_f32_16x16x32_bf16(af[m], bfr[n], acc[m][n], 0, 0, 0);
    __builtin_amdgcn_s_setprio(0);
    barrier_();
    // ---- phase 3: kk=1, hi half
#pragma unroll
    for (int m = 0; m < MF / 2; ++m) af[m] = ardf(cb, 1, MF / 2 + m);
    barrier_();
    __builtin_amdgcn_s_setprio(1);
#pragma unroll
    for (int m = 0; m < MF / 2; ++m)
#pragma unroll
      for (int n = 0; n < NF; ++n)
        acc[MF / 2 + m][n] =
            __builtin_amdgcn_mfma_f32_16x16x32_bf16(af[m], bfr[n], acc[MF / 2 + m][n], 0, 0, 0);
    __builtin_amdgcn_s_setprio(0);
    barrier_();
  }

#pragma unroll
  for (int m = 0; m < MF; ++m) {
    const int row = m0 + wr * (BM / 2) + m * 16 + fq * 4;
#pragma unroll
    for (int n = 0; n < NF; ++n) {
      const int col = n0 + wc * (BN / 4) + n * 16 + fr;
#pragma unroll
      for (int r = 0; r < 4; ++r)
        C[(long)(row + r) * ldc + col] = f2bf(acc[m][n][r]);
    }
  }
}

// Persistent Q/K + VT: 256 blocks, 4-phase body.
__global__ __launch_bounds__(512, 2)
void qkvt_gemm(const unsigned short* __restrict__ Xq, const unsigned short* __restrict__ WQT,
               unsigned short* __restrict__ Q,
               const unsigned short* __restrict__ Xk, const unsigned short* __restrict__ WKT,
               unsigned short* __restrict__ Kk,
               const unsigned short* __restrict__ WVT, const unsigned short* __restrict__ Xv,
               unsigned short* __restrict__ VT) {
  __shared__ __align__(16) char pool[131072];
  const int id = (blockIdx.x & 7) * 32 + (blockIdx.x >> 3);   // 256 % 8 == 0
  if (id < 128)
    gemm_4ph<8, 4>(Xq, WQT, Q, id >> 2, id & 3, 1024,
                   1024, 1024, 1024, pool, pool + 65536);
  else
    gemm_4ph<8, 4>(Xk, WKT, Kk, (id - 128) >> 2, id & 3, 1024,
                   1024, 1024, 1024, pool, pool + 65536);
  __syncthreads();                              // LDS safe to reuse
  gemm_4ph<4, 4>(WVT, Xv, VT, id >> 5, id & 31, 1024,
                 1024, 1024, 8192, pool, pool + 32768);
}

// Scores: S_b = Q_b K_b^T; 128x128 tiles over the causal lower triangle.
__global__ __launch_bounds__(512, 4)
void scores_gemm(const unsigned short* __restrict__ Q, const unsigned short* __restrict__ K,
                 unsigned short* __restrict__ S) {
  __shared__ __align__(16) char pool[65536];
  const int gid = (blockIdx.x & 7) * 68 + (blockIdx.x >> 3);  // 544 = 8*68
  const int bz = gid / 136, t = gid - bz * 136;
  int bm = (int)((__fsqrt_rn(8.0f * t + 1.0f) - 1.0f) * 0.5f);
  while ((bm + 1) * (bm + 2) / 2 <= t) ++bm;
  while (bm * (bm + 1) / 2 > t) --bm;
  const int bn = t - bm * (bm + 1) / 2;
  gemm_body<unsigned short, 4, 2>(Q + (long)bz * 2048 * 1024, K + (long)bz * 2048 * 1024,
                                  S + (long)bz * 2048 * 2048, bm, bn, 1024,
                                  1024, 1024, 2048, pool, pool + 32768);
}

// PV: out_b = P_b V_b; 128x128 tiles, heavy+light pairing.
__global__ __launch_bounds__(512, 4)
void pv_gemm(const unsigned short* __restrict__ P, const unsigned short* __restrict__ VT,
             float* __restrict__ O) {
  __shared__ __align__(16) char pool[65536];
  const int b = blockIdx.x;
  int bm, r;
  if (b < 256) { bm = 15 - (b >> 5); r = b & 31; }
  else         { bm = (b - 256) >> 5; r = b & 31; }
  const int bn = r & 7, bz = r >> 3;
  gemm_body<float, 4, 2>(P + (long)bz * 2048 * 2048, VT + (long)bz * 2048,
                         O + (long)bz * 2048 * 1024, bm, bn, (bm + 1) * 128,
                         2048, 8192, 1024, pool, pool + 32768);
}

// ---------------- causal softmax, vectorized, register-resident -------------
__global__ __launch_bounds__(256)
void softmax_causal(unsigned short* __restrict__ P) {
  const int row = blockIdx.x;              // b*2048 + q
  const int q = row & 2047;
  unsigned short* p = P + (long)row * 2048;
  const int nfill = ((q >> 7) + 1) << 7;   // PV reads up to this 128-boundary
  const int tid = threadIdx.x;
  const int lane = tid & 63, wid = tid >> 6;
  const int i0 = tid * 8;
  __shared__ float red[8];

  float v[8];
  float lmax = -3.0e38f;
  if (i0 <= q) {                           // skip loads past causal boundary
    ushort8 v8 = *(const ushort8*)(p + i0);
#pragma unroll
    for (int j = 0; j < 8; ++j) {
      float f = bf2f(v8[j]);
      f = (i0 + j <= q) ? f : -3.0e38f;
      v[j] = f;
      lmax = fmaxf(lmax, f);
    }
  } else {
#pragma unroll
    for (int j = 0; j < 8; ++j) v[j] = -3.0e38f;
  }
#pragma unroll
  for (int off = 1; off < 64; off <<= 1)
    lmax = fmaxf(lmax, __shfl_xor(lmax, off));
  if (lane == 0) red[wid] = lmax;
  __syncthreads();
  const float mx = fmaxf(fmaxf(red[0], red[1]), fmaxf(red[2], red[3]));

  float lsum = 0.f;
#pragma unroll
  for (int j = 0; j < 8; ++j) {
    float e = __expf(v[j] - mx);           // masked lanes -> exp(-huge) = 0
    v[j] = e;
    lsum += e;
  }
#pragma unroll
  for (int off = 1; off < 64; off <<= 1)
    lsum += __shfl_xor(lsum, off);
  if (lane == 0) red[4 + wid] = lsum;
  __syncthreads();
  const float inv = 1.0f / (red[4] + red[5] + red[6] + red[7]);

  if (i0 < nfill) {
    ushort8 r;
#pragma unroll
    for (int j = 0; j < 8; ++j)
      r[j] = (i0 + j <= q) ? f2bf(v[j] * inv) : (unsigned short)0;
    *(ushort8*)(p + i0) = r;
  }
}

// ---------------------------------------------------------------------------
extern "C" void kernel_launch(void* const* d_in, const int* in_sizes, int n_in,
                              void* d_out, int out_size, void* d_ws, size_t ws_size,
                              hipStream_t stream) {
  const float* Xk = (const float*)d_in[0];
  const float* Xv = (const float*)d_in[1];
  const float* Xq = (const float*)d_in[2];
  const float* WK = (const float*)d_in[3];
  const float* WQ = (const float*)d_in[4];
  const float* WV = (const float*)d_in[5];
  float* out = (float*)d_out;

  unsigned short* ws = (unsigned short*)d_ws;
  const long NE = 8L * 1024 * 1024;          // 8192*1024 elems
  unsigned short* Xqb = ws + 0 * NE;
  unsigned short* Xkb = ws + 1 * NE;
  unsigned short* Xvb = ws + 2 * NE;
  unsigned short* Qb  = ws + 3 * NE;
  unsigned short* Kb  = ws + 4 * NE;
  unsigned short* VTb = ws + 5 * NE;
  unsigned short* WQT = ws + 6 * NE;
  unsigned short* WKT = WQT + 1024 * 1024;
  unsigned short* WVT = WKT + 1024 * 1024;
  unsigned short* Sc  = ws;                  // 2^24 elems, aliases dead Xq+Xk

  dim3 b256(256), b512(512);
  prep<<<15360, b256, 0, stream>>>(Xq, Xk, Xv, Xqb, Xkb, Xvb,
                                   WQ, WK, WV, WQT, WKT, WVT);
  qkvt_gemm<<<256, b512, 0, stream>>>(Xqb, WQT, Qb, Xkb, WKT, Kb, WVT, Xvb, VTb);
  scores_gemm<<<544, b512, 0, stream>>>(Qb, Kb, Sc);
  softmax_causal<<<8192, b256, 0, stream>>>(Sc);
  pv_gemm<<<512, b512, 0, stream>>>(Sc, VTb, out);
}

// Round 12
// 147.638 us; speedup vs baseline: 1.1241x; 1.0714x over previous
//
#include <hip/hip_runtime.h>
#include <stdint.h>

// ---------------------------------------------------------------------------
// AttentionHead: out = softmax_causal((Xq WQ)(Xk WK)^T / sqrt(D)) (Xv WV)
// B=4, S=2048, D=1024.  bf16 MFMA 16x16x32, f32 accumulate.
// Round 12: associativity rewrite — scores = Xq (WQ WK^T) Xk^T:
//   Mt[b][a] = sum_e WK[b][e] WQ[a][e]   (2.1 GF; scale 1/32 folded into WQb)
//   Y  = Xq · M   (B^T GEMM vs Mt)        scores = Y · Xk^T  (no K-proj!)
// Deletes the 17.2 GF K projection.  All GEMMs use the proven 0-conflict
// full-tile-residency body.  Dispatches: prep / [VT+Mt] / Y / scores /
// softmax / pv.
// ---------------------------------------------------------------------------

typedef __attribute__((ext_vector_type(8))) short short8;
typedef __attribute__((ext_vector_type(8))) unsigned short ushort8;
typedef __attribute__((ext_vector_type(4))) float f32x4;

__device__ __forceinline__ unsigned short f2bf(float f) {
  union { float f; unsigned u; } v; v.f = f;
  unsigned u = v.u + 0x7FFFu + ((v.u >> 16) & 1u);   // RNE
  return (unsigned short)(u >> 16);
}
__device__ __forceinline__ float bf2f(unsigned short h) {
  union { unsigned u; float f; } v; v.u = ((unsigned)h) << 16;
  return v.f;
}

__device__ __forceinline__ void gload16(const void* g, void* l) {
  __builtin_amdgcn_global_load_lds(
      (const __attribute__((address_space(1))) unsigned int*)g,
      (__attribute__((address_space(3))) unsigned int*)l, 16, 0, 0);
}

template<int N> __device__ __forceinline__ void vmwait() {
  static_assert(N >= 0 && N <= 8, "vmcnt range");
  if constexpr (N == 0) asm volatile("s_waitcnt vmcnt(0)" ::: "memory");
  else if constexpr (N == 1) asm volatile("s_waitcnt vmcnt(1)" ::: "memory");
  else if constexpr (N == 2) asm volatile("s_waitcnt vmcnt(2)" ::: "memory");
  else if constexpr (N == 3) asm volatile("s_waitcnt vmcnt(3)" ::: "memory");
  else if constexpr (N == 4) asm volatile("s_waitcnt vmcnt(4)" ::: "memory");
  else if constexpr (N == 5) asm volatile("s_waitcnt vmcnt(5)" ::: "memory");
  else if constexpr (N == 6) asm volatile("s_waitcnt vmcnt(6)" ::: "memory");
  else if constexpr (N == 7) asm volatile("s_waitcnt vmcnt(7)" ::: "memory");
  else asm volatile("s_waitcnt vmcnt(8)" ::: "memory");
}
__device__ __forceinline__ void barrier_() { asm volatile("s_barrier" ::: "memory"); }
__device__ __forceinline__ void lgkm0() { asm volatile("s_waitcnt lgkmcnt(0)" ::: "memory"); }

// ---------------- prep: cvt X x3, cvt WQ(scaled)/WK, wtrans WV --------------
__global__ __launch_bounds__(256)
void prep(const float* __restrict__ Xq, const float* __restrict__ Xk,
          const float* __restrict__ Xv,
          unsigned short* __restrict__ Oq, unsigned short* __restrict__ Ok,
          unsigned short* __restrict__ Ov,
          const float* __restrict__ WQ, const float* __restrict__ WK,
          const float* __restrict__ WV,
          unsigned short* __restrict__ WQb, unsigned short* __restrict__ WKb,
          unsigned short* __restrict__ WVT) {
  const int bx = blockIdx.x;
  const int tid = threadIdx.x;
  if (bx < 12288) {                                // X cvt: 4096 blocks/tensor
    const int op = bx >> 12, r = bx & 4095;
    const float* in = op == 0 ? Xq : op == 1 ? Xk : Xv;
    unsigned short* out = op == 0 ? Oq : op == 1 ? Ok : Ov;
    const long i = ((long)r * 256 + tid) * 8;
    float4 a = *(const float4*)(in + i);
    float4 b = *(const float4*)(in + i + 4);
    ushort8 rr;
    rr[0] = f2bf(a.x); rr[1] = f2bf(a.y); rr[2] = f2bf(a.z); rr[3] = f2bf(a.w);
    rr[4] = f2bf(b.x); rr[5] = f2bf(b.y); rr[6] = f2bf(b.z); rr[7] = f2bf(b.w);
    *(ushort8*)(out + i) = rr;
  } else if (bx < 13312) {                         // WQ/WK cvt: 512 blocks each
    const int wi = bx - 12288;                     // 0..1023
    const float* in = wi < 512 ? WQ : WK;
    unsigned short* out = wi < 512 ? WQb : WKb;
    const float scale = wi < 512 ? 0.03125f : 1.0f;  // 1/sqrt(1024) into WQb
    const long i = ((long)(wi & 511) * 256 + tid) * 8;
    float4 a = *(const float4*)(in + i);
    float4 b = *(const float4*)(in + i + 4);
    ushort8 rr;
    rr[0] = f2bf(a.x * scale); rr[1] = f2bf(a.y * scale);
    rr[2] = f2bf(a.z * scale); rr[3] = f2bf(a.w * scale);
    rr[4] = f2bf(b.x * scale); rr[5] = f2bf(b.y * scale);
    rr[6] = f2bf(b.z * scale); rr[7] = f2bf(b.w * scale);
    *(ushort8*)(out + i) = rr;
  } else {                                         // WV transpose: 1024 blocks
    const int rem = bx - 13312;
    __shared__ float tbuf[32][33];
    const int bk = (rem >> 5) * 32, be = (rem & 31) * 32;
    const int tx = tid & 31, ty = tid >> 5;        // (32,8)
#pragma unroll
    for (int j = 0; j < 32; j += 8)
      tbuf[ty + j][tx] = WV[(long)(bk + ty + j) * 1024 + (be + tx)];
    __syncthreads();
#pragma unroll
    for (int j = 0; j < 32; j += 8)
      WVT[(long)(be + ty + j) * 1024 + (bk + tx)] = f2bf(tbuf[tx][ty + j]);
  }
}

// ---------------- B^T-layout bf16 GEMM, full-tile-residency K-loop ----------
// C[m][n] = sum_k A[m][k]*B[n][k].  BM=MF*32, BN=NF*64.  8 waves (2Mx4N).
// LDS [buf][khalf][row][32]; 16B-slot swizzle ^((row>>1)&3)  (0-conflict).
template<typename CT, int MF, int NF>
__device__ __forceinline__ void gemm_body(const unsigned short* __restrict__ A,
                                          const unsigned short* __restrict__ B,
                                          CT* __restrict__ C,
                                          int bm, int bn, int kmax,
                                          int lda, int ldb, int ldc,
                                          char* AL, char* BL) {
  constexpr int BM = MF * 32, BN = NF * 64;
  constexpr int LA = BM / 128, LB = BN / 128;
  constexpr int S = 2 * (LA + LB);

  const int tid = threadIdx.x;
  const int lane = tid & 63, wid = tid >> 6;
  const int wr = wid >> 2, wc = wid & 3;
  const int fr = lane & 15, fq = lane >> 4;
  const int srow = tid >> 2;
  const int scol = (((tid & 3) ^ ((tid >> 3) & 3)) << 3);
  const int m0 = bm * BM, n0 = bn * BN;
  const int nt = kmax >> 6;

  f32x4 acc[MF][NF] = {};

  const unsigned short* As = A + (long)(m0 + srow) * lda + scol;
  const unsigned short* Bs = B + (long)(n0 + srow) * ldb + scol;

  auto stageTile = [&](int b, int kt) {
#pragma unroll
    for (int h = 0; h < 2; ++h) {
#pragma unroll
      for (int l = 0; l < LA; ++l)
        gload16(As + (long)l * 128 * lda + kt * 64 + h * 32,
                AL + b * (BM * 128) + h * (BM * 64) + l * 8192 + tid * 16);
#pragma unroll
      for (int l = 0; l < LB; ++l)
        gload16(Bs + (long)l * 128 * ldb + kt * 64 + h * 32,
                BL + b * (BN * 128) + h * (BN * 64) + l * 8192 + tid * 16);
    }
  };

  const int aoff = (wr * (BM / 2) + fr) * 64 + ((fq ^ ((fr >> 1) & 3)) << 4);
  const int boff = (wc * (BN / 4) + fr) * 64 + ((fq ^ ((fr >> 1) & 3)) << 4);
  auto ardf = [&](int b, int kk, int m) -> short8 {
    return *(const short8*)(AL + b * (BM * 128) + kk * (BM * 64) + aoff + m * 1024);
  };
  auto brdf = [&](int b, int kk, int n) -> short8 {
    return *(const short8*)(BL + b * (BN * 128) + kk * (BN * 64) + boff + n * 1024);
  };

  stageTile(0, 0);

  for (int u = 0; u < nt; ++u) {
    const int cb = u & 1, nb = cb ^ 1;
    lgkm0();
    barrier_();
    if (u + 1 < nt) { stageTile(nb, u + 1); vmwait<S>(); }
    else            { vmwait<0>(); }
    barrier_();
#pragma unroll
    for (int kk = 0; kk < 2; ++kk) {
      short8 bfr[NF], af[MF / 2];
#pragma unroll
      for (int n = 0; n < NF; ++n) bfr[n] = brdf(cb, kk, n);
#pragma unroll
      for (int m = 0; m < MF / 2; ++m) af[m] = ardf(cb, kk, m);
      __builtin_amdgcn_s_setprio(1);
#pragma unroll
      for (int m = 0; m < MF / 2; ++m)
#pragma unroll
        for (int n = 0; n < NF; ++n)
          acc[m][n] = __builtin_amdgcn_mfma_f32_16x16x32_bf16(af[m], bfr[n], acc[m][n], 0, 0, 0);
      __builtin_amdgcn_s_setprio(0);
#pragma unroll
      for (int m = 0; m < MF / 2; ++m) af[m] = ardf(cb, kk, MF / 2 + m);
      __builtin_amdgcn_s_setprio(1);
#pragma unroll
      for (int m = 0; m < MF / 2; ++m)
#pragma unroll
        for (int n = 0; n < NF; ++n)
          acc[MF / 2 + m][n] =
              __builtin_amdgcn_mfma_f32_16x16x32_bf16(af[m], bfr[n], acc[MF / 2 + m][n], 0, 0, 0);
      __builtin_amdgcn_s_setprio(0);
    }
  }

  // C/D layout: col = lane&15, row = (lane>>4)*4 + reg
#pragma unroll
  for (int m = 0; m < MF; ++m) {
    const int row = m0 + wr * (BM / 2) + m * 16 + fq * 4;
#pragma unroll
    for (int n = 0; n < NF; ++n) {
      const int col = n0 + wc * (BN / 4) + n * 16 + fr;
#pragma unroll
      for (int r = 0; r < 4; ++r) {
        float v = acc[m][n][r];
        if constexpr (sizeof(CT) == 2)
          C[(long)(row + r) * ldc + col] = (CT)f2bf(v);
        else
          C[(long)(row + r) * ldc + col] = (CT)v;
      }
    }
  }
}

// D2: VT quarters (512) + Mt tiles (64) = 576 blocks, 128^2 tiles, 2/CU.
//   VT[1024][8192] = WVT * Xv^T;  Mt[b][a] = sum_e WK[b][e] WQ[a][e].
__global__ __launch_bounds__(512, 4)
void d2_gemm(const unsigned short* __restrict__ WVT, const unsigned short* __restrict__ Xvb,
             unsigned short* __restrict__ VT,
             const unsigned short* __restrict__ WKb, const unsigned short* __restrict__ WQb,
             unsigned short* __restrict__ Mt) {
  __shared__ __align__(16) char pool[65536];
  const int id = (blockIdx.x & 7) * 72 + (blockIdx.x >> 3);   // 576 = 8*72
  if (id < 512)
    gemm_body<unsigned short, 4, 2>(WVT, Xvb, VT, id >> 6, id & 63, 1024,
                                    1024, 1024, 8192, pool, pool + 32768);
  else {
    const int t = id - 512;
    gemm_body<unsigned short, 4, 2>(WKb, WQb, Mt, t >> 3, t & 7, 1024,
                                    1024, 1024, 1024, pool, pool + 32768);
  }
}

// D3: Y = Xq * M  (B^T vs Mt): 512 tiles 128^2, exactly 2/CU one round.
__global__ __launch_bounds__(512, 4)
void y_gemm(const unsigned short* __restrict__ Xqb, const unsigned short* __restrict__ Mt,
            unsigned short* __restrict__ Y) {
  __shared__ __align__(16) char pool[65536];
  const int id = (blockIdx.x & 7) * 64 + (blockIdx.x >> 3);   // 512 = 8*64
  gemm_body<unsigned short, 4, 2>(Xqb, Mt, Y, id >> 3, id & 7, 1024,
                                  1024, 1024, 1024, pool, pool + 32768);
}

// Scores: S_b = Y_b Xk_b^T; 128x128 tiles over the causal lower triangle.
__global__ __launch_bounds__(512, 4)
void scores_gemm(const unsigned short* __restrict__ Y, const unsigned short* __restrict__ Xkb,
                 unsigned short* __restrict__ S) {
  __shared__ __align__(16) char pool[65536];
  const int gid = (blockIdx.x & 7) * 68 + (blockIdx.x >> 3);  // 544 = 8*68
  const int bz = gid / 136, t = gid - bz * 136;
  int bm = (int)((__fsqrt_rn(8.0f * t + 1.0f) - 1.0f) * 0.5f);
  while ((bm + 1) * (bm + 2) / 2 <= t) ++bm;
  while (bm * (bm + 1) / 2 > t) --bm;
  const int bn = t - bm * (bm + 1) / 2;
  gemm_body<unsigned short, 4, 2>(Y + (long)bz * 2048 * 1024, Xkb + (long)bz * 2048 * 1024,
                                  S + (long)bz * 2048 * 2048, bm, bn, 1024,
                                  1024, 1024, 2048, pool, pool + 32768);
}

// PV: out_b = P_b V_b; 128x128 tiles, heavy+light pairing.
__global__ __launch_bounds__(512, 4)
void pv_gemm(const unsigned short* __restrict__ P, const unsigned short* __restrict__ VT,
             float* __restrict__ O) {
  __shared__ __align__(16) char pool[65536];
  const int b = blockIdx.x;
  int bm, r;
  if (b < 256) { bm = 15 - (b >> 5); r = b & 31; }
  else         { bm = (b - 256) >> 5; r = b & 31; }
  const int bn = r & 7, bz = r >> 3;
  gemm_body<float, 4, 2>(P + (long)bz * 2048 * 2048, VT + (long)bz * 2048,
                         O + (long)bz * 2048 * 1024, bm, bn, (bm + 1) * 128,
                         2048, 8192, 1024, pool, pool + 32768);
}

// ---------------- causal softmax, vectorized, register-resident -------------
__global__ __launch_bounds__(256)
void softmax_causal(unsigned short* __restrict__ P) {
  const int row = blockIdx.x;              // b*2048 + q
  const int q = row & 2047;
  unsigned short* p = P + (long)row * 2048;
  const int nfill = ((q >> 7) + 1) << 7;   // PV reads up to this 128-boundary
  const int tid = threadIdx.x;
  const int lane = tid & 63, wid = tid >> 6;
  const int i0 = tid * 8;
  __shared__ float red[8];

  float v[8];
  float lmax = -3.0e38f;
  if (i0 <= q) {                           // skip loads past causal boundary
    ushort8 v8 = *(const ushort8*)(p + i0);
#pragma unroll
    for (int j = 0; j < 8; ++j) {
      float f = bf2f(v8[j]);
      f = (i0 + j <= q) ? f : -3.0e38f;
      v[j] = f;
      lmax = fmaxf(lmax, f);
    }
  } else {
#pragma unroll
    for (int j = 0; j < 8; ++j) v[j] = -3.0e38f;
  }
#pragma unroll
  for (int off = 1; off < 64; off <<= 1)
    lmax = fmaxf(lmax, __shfl_xor(lmax, off));
  if (lane == 0) red[wid] = lmax;
  __syncthreads();
  const float mx = fmaxf(fmaxf(red[0], red[1]), fmaxf(red[2], red[3]));

  float lsum = 0.f;
#pragma unroll
  for (int j = 0; j < 8; ++j) {
    float e = __expf(v[j] - mx);           // masked lanes -> exp(-huge) = 0
    v[j] = e;
    lsum += e;
  }
#pragma unroll
  for (int off = 1; off < 64; off <<= 1)
    lsum += __shfl_xor(lsum, off);
  if (lane == 0) red[4 + wid] = lsum;
  __syncthreads();
  const float inv = 1.0f / (red[4] + red[5] + red[6] + red[7]);

  if (i0 < nfill) {
    ushort8 r;
#pragma unroll
    for (int j = 0; j < 8; ++j)
      r[j] = (i0 + j <= q) ? f2bf(v[j] * inv) : (unsigned short)0;
    *(ushort8*)(p + i0) = r;
  }
}

// ---------------------------------------------------------------------------
extern "C" void kernel_launch(void* const* d_in, const int* in_sizes, int n_in,
                              void* d_out, int out_size, void* d_ws, size_t ws_size,
                              hipStream_t stream) {
  const float* Xk = (const float*)d_in[0];
  const float* Xv = (const float*)d_in[1];
  const float* Xq = (const float*)d_in[2];
  const float* WK = (const float*)d_in[3];
  const float* WQ = (const float*)d_in[4];
  const float* WV = (const float*)d_in[5];
  float* out = (float*)d_out;

  unsigned short* ws = (unsigned short*)d_ws;
  const long NE = 8L * 1024 * 1024;          // 8192*1024 elems
  unsigned short* Xkb = ws + 0 * NE;         // live through scores
  unsigned short* Xqb = ws + 1 * NE;         // dead after y_gemm
  unsigned short* Xvb = ws + 2 * NE;         // dead after d2_gemm
  unsigned short* Yb  = ws + 3 * NE;         // live through scores
  unsigned short* VTb = ws + 4 * NE;         // live through pv
  unsigned short* WQb = ws + 5 * NE;
  unsigned short* WKb = WQb + 1024 * 1024;
  unsigned short* WVT = WKb + 1024 * 1024;
  unsigned short* Mtb = WVT + 1024 * 1024;
  unsigned short* Sc  = ws + 1 * NE;         // 2NE span: aliases dead Xqb+Xvb

  dim3 b256(256), b512(512);
  prep<<<14336, b256, 0, stream>>>(Xq, Xk, Xv, Xqb, Xkb, Xvb,
                                   WQ, WK, WV, WQb, WKb, WVT);
  d2_gemm<<<576, b512, 0, stream>>>(WVT, Xvb, VTb, WKb, WQb, Mtb);
  y_gemm<<<512, b512, 0, stream>>>(Xqb, Mtb, Yb);
  scores_gemm<<<544, b512, 0, stream>>>(Yb, Xkb, Sc);
  softmax_causal<<<8192, b256, 0, stream>>>(Sc);
  pv_gemm<<<512, b512, 0, stream>>>(Sc, VTb, out);
}